// Round 1
// 471.839 us; speedup vs baseline: 1.0033x; 1.0033x over previous
//
#include <hip/hip_runtime.h>

// Problem constants (from reference):
//   table:   [1048576, 64] f32   (268 MB)
//   weights: [67108864, 1] f32   (268 MB)
//   idx0:    [32768, 32] i32
//   idx1:    [32768, 32] i32
//   out:     [32768, 64] f32 = mean over 32 chunks of table[idx0]*weights[idx1]
#define N_B 32768
#define N_CHUNKS 32
#define DIM 64

// Wave-per-row layout: each 64-lane wave owns one output row, lane = dim.
//  - idx0/idx1 for the row loaded once, coalesced (lanes 0..31 hold chunk c = lane,
//    lanes 32..63 duplicate them so readlane sources are always valid).
//  - all 32 gathered weights fetched by ONE instruction (lane c -> weights[idx1[c]]).
//  - 32 table-row loads are mutually independent, each is ONE contiguous 256B
//    segment (base scalarized via readlane -> SGPR base + lane*4 offset),
//    so the full 8KB of row data is in flight per wave at once.
// 4 waves/block, 256 threads, grid = 8192 blocks; ~40-48 VGPR -> full occupancy.
__global__ __launch_bounds__(256) void WeightedHashEmbedding_kernel(
    const float* __restrict__ table,
    const float* __restrict__ weights,
    const int*   __restrict__ idx0,
    const int*   __restrict__ idx1,
    float*       __restrict__ out)
{
    const int lane = threadIdx.x & 63;
    const int wid  = threadIdx.x >> 6;          // wave within block: 0..3
    const int b    = blockIdx.x * 4 + wid;      // one batch row per wave

    const int c  = lane & 31;                   // chunk id this lane caches (dup in hi half)
    const int i0 = idx0[b * N_CHUNKS + c];      // coalesced 128B (dup halves)
    const int i1 = idx1[b * N_CHUNKS + c];      // coalesced 128B (dup halves)
    const float wv = weights[i1];               // ONE gather instr: 32 unique random lines

    // Gather phase: 32 independent 256B row reads, all outstanding together.
    float v[N_CHUNKS];
    #pragma unroll
    for (int cc = 0; cc < N_CHUNKS; ++cc) {
        const int row = __builtin_amdgcn_readlane(i0, cc);   // wave-uniform -> SGPR base
        v[cc] = table[(size_t)row * DIM + lane];             // saddr + lane*4: one 256B segment
    }

    // Reduce phase: weights broadcast via readlane (SGPR operand in v_fmac).
    float acc = 0.f;
    #pragma unroll
    for (int cc = 0; cc < N_CHUNKS; ++cc) {
        const float w = __uint_as_float(__builtin_amdgcn_readlane(__float_as_uint(wv), cc));
        acc += v[cc] * w;
    }

    out[(size_t)b * DIM + lane] = acc * (1.0f / (float)N_CHUNKS);
}

extern "C" void kernel_launch(void* const* d_in, const int* in_sizes, int n_in,
                              void* d_out, int out_size, void* d_ws, size_t ws_size,
                              hipStream_t stream) {
    const float* table   = (const float*)d_in[0];
    const float* weights = (const float*)d_in[1];
    const int*   idx0    = (const int*)d_in[2];
    const int*   idx1    = (const int*)d_in[3];
    float*       out     = (float*)d_out;

    const int rows_per_block = 4;                // 4 waves/block, one row per wave
    const int grid = N_B / rows_per_block;       // 8192 blocks
    WeightedHashEmbedding_kernel<<<grid, 256, 0, stream>>>(table, weights, idx0, idx1, out);
}

// Round 2
// 468.571 us; speedup vs baseline: 1.0103x; 1.0070x over previous
//
#include <hip/hip_runtime.h>

// Problem constants (from reference):
//   table:   [1048576, 64] f32   (268 MB)
//   weights: [67108864, 1] f32   (268 MB)
//   idx0:    [32768, 32] i32
//   idx1:    [32768, 32] i32
//   out:     [32768, 64] f32 = mean over 32 chunks of table[idx0]*weights[idx1]
#define N_B 32768
#define N_CHUNKS 32
#define DIM 64

// Wave-per-row layout (round-1 structure, verified correct):
//   each 64-lane wave owns one output row, lane = dim; 32 independent 256B
//   table-row loads in flight per wave; weights/idx fetched once per row.
//
// Round-2 change: L3 capacity management. The 268MB table ALMOST fits the
// 256MB Infinity Cache, and ~37% of the 1M row gathers are repeat touches
// (random with replacement). Every other stream (weights: 1M random 4B
// gathers = 64-128MB of line-granular fetch with ZERO reuse; idx: read-once;
// out: write-once) is marked non-temporal so it doesn't thrash the L3
// capacity the table needs. Table loads stay cacheable.
__global__ __launch_bounds__(256) void WeightedHashEmbedding_kernel(
    const float* __restrict__ table,
    const float* __restrict__ weights,
    const int*   __restrict__ idx0,
    const int*   __restrict__ idx1,
    float*       __restrict__ out)
{
    const int lane = threadIdx.x & 63;
    const int wid  = threadIdx.x >> 6;          // wave within block: 0..3
    const int b    = blockIdx.x * 4 + wid;      // one batch row per wave

    const int c  = lane & 31;                   // chunk id this lane caches (dup in hi half)
    const int i0 = __builtin_nontemporal_load(idx0 + b * N_CHUNKS + c);   // read-once stream
    const int i1 = __builtin_nontemporal_load(idx1 + b * N_CHUNKS + c);   // read-once stream
    const float wv = __builtin_nontemporal_load(weights + i1);            // zero-reuse gather

    // Gather phase: 32 independent 256B row reads, all outstanding together.
    // CACHEABLE: repeats should hit the Infinity Cache now that the other
    // streams bypass it.
    float v[N_CHUNKS];
    #pragma unroll
    for (int cc = 0; cc < N_CHUNKS; ++cc) {
        const int row = __builtin_amdgcn_readlane(i0, cc);   // wave-uniform -> SGPR base
        v[cc] = table[(size_t)row * DIM + lane];             // saddr + lane*4: one 256B segment
    }

    // Reduce phase: weights broadcast via readlane (SGPR operand in v_fmac).
    float acc = 0.f;
    #pragma unroll
    for (int cc = 0; cc < N_CHUNKS; ++cc) {
        const float w = __uint_as_float(__builtin_amdgcn_readlane(__float_as_uint(wv), cc));
        acc = fmaf(v[cc], w, acc);
    }

    __builtin_nontemporal_store(acc * (1.0f / (float)N_CHUNKS),
                                out + (size_t)b * DIM + lane);   // write-once stream
}

extern "C" void kernel_launch(void* const* d_in, const int* in_sizes, int n_in,
                              void* d_out, int out_size, void* d_ws, size_t ws_size,
                              hipStream_t stream) {
    const float* table   = (const float*)d_in[0];
    const float* weights = (const float*)d_in[1];
    const int*   idx0    = (const int*)d_in[2];
    const int*   idx1    = (const int*)d_in[3];
    float*       out     = (float*)d_out;

    const int rows_per_block = 4;                // 4 waves/block, one row per wave
    const int grid = N_B / rows_per_block;       // 8192 blocks
    WeightedHashEmbedding_kernel<<<grid, 256, 0, stream>>>(table, weights, idx0, idx1, out);
}

// Round 3
// 467.580 us; speedup vs baseline: 1.0124x; 1.0021x over previous
//
#include <hip/hip_runtime.h>

// Problem constants (from reference):
//   table:   [1048576, 64] f32   (268 MB)
//   weights: [67108864, 1] f32   (268 MB)
//   idx0:    [32768, 32] i32
//   idx1:    [32768, 32] i32
//   out:     [32768, 64] f32 = mean over 32 chunks of table[idx0]*weights[idx1]
#define N_B 32768
#define N_CHUNKS 32
#define DIM 64
#define ROWS_PER_WAVE 4

// Wave-per-row layout (verified) + round-3 change: persistent 4-rows-per-wave
// with cross-row software pipelining. Steady-state order per row r:
//   1. prefetch idx0/idx1 for row r+1          (2 coalesced loads)
//   2. issue 32 independent 256B table loads for row r (i0 already in hand)
//   3. issue weights gather for row r+1        (compiler waits vmcnt(32):
//      only the 2 idx prefetches drain — table loads stay in flight)
//   4. reduce row r (waits the table loads; wv for row r loaded last iter)
//   5. store, rotate pipeline regs
// This removes the serial idx->table HBM latency chain from the steady state;
// the wave always has ~34 loads outstanding. Non-table streams stay
// non-temporal (L3 reserved for table rows).
__global__ __launch_bounds__(256) void WeightedHashEmbedding_kernel(
    const float* __restrict__ table,
    const float* __restrict__ weights,
    const int*   __restrict__ idx0,
    const int*   __restrict__ idx1,
    float*       __restrict__ out)
{
    const int lane = threadIdx.x & 63;
    const int wid  = threadIdx.x >> 6;                  // wave in block: 0..3
    const int b0   = (blockIdx.x * 4 + wid) * ROWS_PER_WAVE;  // first of 4 rows
    const int c    = lane & 31;                         // chunk id (dup in hi half)

    // Prologue: row b0's indices + weight (2 serial latencies, amortized /4).
    int   i0 = __builtin_nontemporal_load(idx0 + b0 * N_CHUNKS + c);
    int   i1 = __builtin_nontemporal_load(idx1 + b0 * N_CHUNKS + c);
    float wv = __builtin_nontemporal_load(weights + i1);

    #pragma unroll
    for (int r = 0; r < ROWS_PER_WAVE; ++r) {
        const int b = b0 + r;

        // (1) prefetch next row's index vectors first (oldest in vmcnt order)
        int i0n = 0, i1n = 0;
        if (r + 1 < ROWS_PER_WAVE) {
            i0n = __builtin_nontemporal_load(idx0 + (b + 1) * N_CHUNKS + c);
            i1n = __builtin_nontemporal_load(idx1 + (b + 1) * N_CHUNKS + c);
        }

        // (2) 32 independent 256B row reads for the CURRENT row, all in flight
        float v[N_CHUNKS];
        #pragma unroll
        for (int cc = 0; cc < N_CHUNKS; ++cc) {
            const int row = __builtin_amdgcn_readlane(i0, cc);  // SGPR base
            v[cc] = table[(size_t)row * DIM + lane];            // one 256B segment
        }

        // (3) next row's weights gather — only drains the 2 idx prefetches
        float wvn = 0.f;
        if (r + 1 < ROWS_PER_WAVE) {
            wvn = __builtin_nontemporal_load(weights + i1n);
        }

        // (4) reduce current row: weights broadcast via readlane (SGPR fmac)
        float acc = 0.f;
        #pragma unroll
        for (int cc = 0; cc < N_CHUNKS; ++cc) {
            const float w = __uint_as_float(
                __builtin_amdgcn_readlane(__float_as_uint(wv), cc));
            acc = fmaf(v[cc], w, acc);
        }

        // (5) store and rotate
        __builtin_nontemporal_store(acc * (1.0f / (float)N_CHUNKS),
                                    out + (size_t)b * DIM + lane);
        i0 = i0n; i1 = i1n; wv = wvn;
    }
}

extern "C" void kernel_launch(void* const* d_in, const int* in_sizes, int n_in,
                              void* d_out, int out_size, void* d_ws, size_t ws_size,
                              hipStream_t stream) {
    const float* table   = (const float*)d_in[0];
    const float* weights = (const float*)d_in[1];
    const int*   idx0    = (const int*)d_in[2];
    const int*   idx1    = (const int*)d_in[3];
    float*       out     = (float*)d_out;

    // 4 waves/block x 4 rows/wave = 16 rows/block -> 2048 blocks (8/CU)
    const int grid = N_B / (4 * ROWS_PER_WAVE);
    WeightedHashEmbedding_kernel<<<grid, 256, 0, stream>>>(table, weights, idx0, idx1, out);
}